// Round 4
// baseline (3755.729 us; speedup 1.0000x reference)
//
#include <hip/hip_runtime.h>
#include <hip/hip_bf16.h>
#include <cstdint>

#define A_N   100000   // atoms
#define B_N   200000   // bonds
#define MAXNB 6
#define AFD   133
#define BFD   147
#define HID   512
#define NMOL  8192

typedef __attribute__((ext_vector_type(8))) short bf16x8;
typedef __attribute__((ext_vector_type(4))) float f32x4;

__device__ __forceinline__ unsigned short f2b(float f) {
    unsigned u = __builtin_bit_cast(unsigned, f);
    u += 0x7fffu + ((u >> 16) & 1u);
    return (unsigned short)(u >> 16);
}
__device__ __forceinline__ float blo(unsigned u) { return __builtin_bit_cast(float, u << 16); }
__device__ __forceinline__ float bhi(unsigned u) { return __builtin_bit_cast(float, u & 0xffff0000u); }
__device__ __forceinline__ unsigned pack2f(float a, float b) {
    return (unsigned)f2b(a) | ((unsigned)f2b(b) << 16);
}

// ---------------- diagnostic fallback (ws too small) ----------------
__global__ __launch_bounds__(256) void k_diag(float* __restrict__ out, int n, float val) {
    int i = blockIdx.x * 256 + threadIdx.x;
    if (i < n) out[i] = val;
}

// ---------------- weight transpose + cast ----------------
// WiT[n][k]   : k 0..146 = Wi[k][n], 147..159 = 0                          (512 x 160, row-major k)
// WcatB tile-major: [(k/32)*512 + n][k%32] ; logical k: 0..511 Wh, 512..658 Wi, 659.. 0
// WoT[n][k]   : k 0..132 = Wo[k][n], 133..159 = 0, 160..671 = Wo[k-27][n]  (512 x 672)
__global__ __launch_bounds__(256) void k_weights(
    const float* __restrict__ Wi, const float* __restrict__ Wh, const float* __restrict__ Wo,
    unsigned short* __restrict__ WiT, unsigned short* __restrict__ WcatB, unsigned short* __restrict__ WoT)
{
    int n = blockIdx.x, t = threadIdx.x;
    for (int k = t; k < 160; k += 256)
        WiT[(size_t)n * 160 + k] = (k < BFD) ? f2b(Wi[(size_t)k * HID + n]) : (unsigned short)0;
    for (int k = t; k < 672; k += 256) {
        unsigned short v;
        if (k < HID)             v = f2b(Wh[(size_t)k * HID + n]);
        else if (k < HID + BFD)  v = f2b(Wi[(size_t)(k - HID) * HID + n]);
        else                     v = 0;
        WcatB[((size_t)(k >> 5) * 512 + n) * 32 + (k & 31)] = v;
    }
    for (int k = t; k < 672; k += 256) {
        unsigned short v;
        if (k < AFD)       v = f2b(Wo[(size_t)k * HID + n]);
        else if (k < 160)  v = 0;
        else               v = f2b(Wo[(size_t)(k - 27) * HID + n]);
        WoT[(size_t)n * 672 + k] = v;
    }
}

// ---------------- GEMM 1: msg = relu(f_bonds @ W_i) ----------------
__global__ __launch_bounds__(256) void k_gemm_wi(
    const float* __restrict__ fb, const unsigned short* __restrict__ WiT,
    unsigned short* __restrict__ msg)
{
    __shared__ unsigned short As[128][32];
    __shared__ unsigned short Bs[128][32];
    const int bm = blockIdx.y, bn = blockIdx.x;
    const int row0 = bm * 128, col0 = bn * 128;
    const int tid = threadIdx.x, lane = tid & 63, wid = tid >> 6;
    const int wm = wid >> 1, wn = wid & 1;
    const int r0 = tid >> 2, c0 = tid & 3, r1 = 64 + r0;
    const int wsw = (c0 ^ ((r0 >> 1) & 3)) * 8;       // write swizzle (same for r0,r1)
    const int rsw = ((lane >> 4) ^ (((lane & 15) >> 1) & 3)) * 8;  // read swizzle
    f32x4 acc[4][4] = {};

    const float* pf0 = fb + (size_t)min(row0 + r0, B_N - 1) * BFD;
    const float* pf1 = fb + (size_t)min(row0 + r1, B_N - 1) * BFD;

    for (int k0 = 0; k0 < 160; k0 += 32) {
        __syncthreads();
        {
            int kb = k0 + c0 * 8;
            uint4 q; float v[8];
#pragma unroll
            for (int i = 0; i < 8; i++) { int kg = kb + i; v[i] = (kg < BFD) ? pf0[kg] : 0.f; }
            q.x = pack2f(v[0], v[1]); q.y = pack2f(v[2], v[3]); q.z = pack2f(v[4], v[5]); q.w = pack2f(v[6], v[7]);
            *(uint4*)&As[r0][wsw] = q;
#pragma unroll
            for (int i = 0; i < 8; i++) { int kg = kb + i; v[i] = (kg < BFD) ? pf1[kg] : 0.f; }
            q.x = pack2f(v[0], v[1]); q.y = pack2f(v[2], v[3]); q.z = pack2f(v[4], v[5]); q.w = pack2f(v[6], v[7]);
            *(uint4*)&As[r1][wsw] = q;
        }
        *(uint4*)&Bs[r0][wsw] = *(const uint4*)(WiT + (size_t)(col0 + r0) * 160 + k0 + c0 * 8);
        *(uint4*)&Bs[r1][wsw] = *(const uint4*)(WiT + (size_t)(col0 + r1) * 160 + k0 + c0 * 8);
        __syncthreads();

        bf16x8 af[4], bfr[4];
#pragma unroll
        for (int m = 0; m < 4; m++) af[m] = *(const bf16x8*)&As[wm * 64 + m * 16 + (lane & 15)][rsw];
#pragma unroll
        for (int n = 0; n < 4; n++) bfr[n] = *(const bf16x8*)&Bs[wn * 64 + n * 16 + (lane & 15)][rsw];
#pragma unroll
        for (int m = 0; m < 4; m++)
#pragma unroll
            for (int n = 0; n < 4; n++)
                acc[m][n] = __builtin_amdgcn_mfma_f32_16x16x32_bf16(af[m], bfr[n], acc[m][n], 0, 0, 0);
    }

#pragma unroll
    for (int m = 0; m < 4; m++) {
        int rbase = row0 + wm * 64 + m * 16 + (lane >> 4) * 4;
#pragma unroll
        for (int n = 0; n < 4; n++) {
            int cg = col0 + wn * 64 + n * 16 + (lane & 15);
#pragma unroll
            for (int r = 0; r < 4; r++) {
                int rg = rbase + r;
                if (rg < B_N) {
                    float v = acc[m][n][r];
                    msg[(size_t)rg * HID + cg] = f2b(v > 0.f ? v : 0.f);
                }
            }
        }
    }
}

// ---------------- fused hot GEMM: msg_out = relu([gather-delta | f_bonds] @ [W_h; W_i]) ----------------
// one block = 128 rows x full 512 cols; 8 waves (2x4); delta computed on the fly from msg_in
__global__ __launch_bounds__(512, 2) void k_gemm_wh_fused(
    const float* __restrict__ fb,
    const unsigned short* __restrict__ msg_in,
    const unsigned short* __restrict__ WcatB,
    const int* __restrict__ a2b, const int* __restrict__ b2a, const int* __restrict__ b2revb,
    unsigned short* __restrict__ msg_out)
{
    __shared__ unsigned short As[128][32];
    __shared__ unsigned short Bs[512][32];
    __shared__ int nbi[128][8];

    const int bm = blockIdx.x;
    const int row0 = bm * 128;
    const int tid = threadIdx.x;
    const int lane = tid & 63, wid = tid >> 6;
    const int wm = wid >> 2, wn = wid & 3;

    if (tid < 128) {
        int b = min(row0 + tid, B_N - 1);
        int atom = b2a[b];
        const int* nb = a2b + (size_t)atom * MAXNB;
#pragma unroll
        for (int j = 0; j < MAXNB; j++) nbi[tid][j] = nb[j];
        nbi[tid][6] = b2revb[b];
    }

    const int srow = tid >> 2;                 // staging row 0..127
    const int schunk = tid & 3;                // 16B chunk 0..3
    const int sb = min(row0 + srow, B_N - 1);  // clamped bond id for fb staging
    const int wswA = (schunk ^ ((srow >> 1) & 3)) * 8;                 // A write swizzle
    const int rsw  = ((lane >> 4) ^ (((lane & 15) >> 1) & 3)) * 8;     // frag read swizzle

    f32x4 acc[4][8] = {};
    uint4 ga[7];      // gathered 16B segments (delta region)
    float fa8[8];     // fb-region staging
    uint4 gb[4];      // B staging regs
    int idx[7];

    __syncthreads();  // nbi visible
#pragma unroll
    for (int j = 0; j < 7; j++) idx[j] = nbi[srow][j];

#define LOAD_A_DELTA(kt) do { \
        int koff = (kt) * 32 + schunk * 8; \
        _Pragma("unroll") \
        for (int j = 0; j < 7; j++) \
            ga[j] = *(const uint4*)(msg_in + (size_t)idx[j] * HID + koff); \
    } while (0)
#define LOAD_A_FB(kt) do { \
        int kb = (kt) * 32 - HID + schunk * 8; \
        _Pragma("unroll") \
        for (int i = 0; i < 8; i++) { int kg = kb + i; fa8[i] = (kg < BFD) ? fb[(size_t)sb * BFD + kg] : 0.f; } \
    } while (0)
#define LOAD_B(kt) do { \
        const unsigned short* p = WcatB + ((size_t)(kt) * 512 + tid) * 32; \
        gb[0] = *(const uint4*)(p); gb[1] = *(const uint4*)(p + 8); \
        gb[2] = *(const uint4*)(p + 16); gb[3] = *(const uint4*)(p + 24); \
    } while (0)
#define WRITE_A_DELTA() do { \
        float s[8]; \
        _Pragma("unroll") \
        for (int i = 0; i < 8; i++) s[i] = 0.f; \
        _Pragma("unroll") \
        for (int j = 0; j < 6; j++) { \
            s[0] += blo(ga[j].x); s[1] += bhi(ga[j].x); s[2] += blo(ga[j].y); s[3] += bhi(ga[j].y); \
            s[4] += blo(ga[j].z); s[5] += bhi(ga[j].z); s[6] += blo(ga[j].w); s[7] += bhi(ga[j].w); \
        } \
        s[0] -= blo(ga[6].x); s[1] -= bhi(ga[6].x); s[2] -= blo(ga[6].y); s[3] -= bhi(ga[6].y); \
        s[4] -= blo(ga[6].z); s[5] -= bhi(ga[6].z); s[6] -= blo(ga[6].w); s[7] -= bhi(ga[6].w); \
        uint4 q; q.x = pack2f(s[0], s[1]); q.y = pack2f(s[2], s[3]); q.z = pack2f(s[4], s[5]); q.w = pack2f(s[6], s[7]); \
        *(uint4*)&As[srow][wswA] = q; \
    } while (0)
#define WRITE_A_FB() do { \
        uint4 q; q.x = pack2f(fa8[0], fa8[1]); q.y = pack2f(fa8[2], fa8[3]); \
        q.z = pack2f(fa8[4], fa8[5]); q.w = pack2f(fa8[6], fa8[7]); \
        *(uint4*)&As[srow][wswA] = q; \
    } while (0)
#define WRITE_B() do { \
        int bsw = (tid >> 1) & 3; \
        *(uint4*)&Bs[tid][(0 ^ bsw) * 8] = gb[0]; *(uint4*)&Bs[tid][(1 ^ bsw) * 8] = gb[1]; \
        *(uint4*)&Bs[tid][(2 ^ bsw) * 8] = gb[2]; *(uint4*)&Bs[tid][(3 ^ bsw) * 8] = gb[3]; \
    } while (0)
#define COMPUTE() do { \
        bf16x8 af[4], bfr[8]; \
        _Pragma("unroll") \
        for (int m = 0; m < 4; m++) af[m] = *(const bf16x8*)&As[wm * 64 + m * 16 + (lane & 15)][rsw]; \
        _Pragma("unroll") \
        for (int n = 0; n < 8; n++) bfr[n] = *(const bf16x8*)&Bs[wn * 128 + n * 16 + (lane & 15)][rsw]; \
        _Pragma("unroll") \
        for (int m = 0; m < 4; m++) \
        _Pragma("unroll") \
        for (int n = 0; n < 8; n++) \
            acc[m][n] = __builtin_amdgcn_mfma_f32_16x16x32_bf16(af[m], bfr[n], acc[m][n], 0, 0, 0); \
    } while (0)

    LOAD_A_DELTA(0);
    LOAD_B(0);
    for (int kt = 0; kt < 16; ++kt) {       // delta region: k = 0..511
        __syncthreads();                     // LDS free (prev compute done)
        WRITE_A_DELTA();
        WRITE_B();
        if (kt < 15) { LOAD_A_DELTA(kt + 1); LOAD_B(kt + 1); }
        else         { LOAD_A_FB(16);        LOAD_B(16);     }
        __syncthreads();                     // LDS ready
        COMPUTE();
    }
    for (int kt = 16; kt < 21; ++kt) {      // bond-feature region: k = 512..671
        __syncthreads();
        WRITE_A_FB();
        WRITE_B();
        if (kt < 20) { LOAD_A_FB(kt + 1); LOAD_B(kt + 1); }
        __syncthreads();
        COMPUTE();
    }

#pragma unroll
    for (int m = 0; m < 4; m++) {
        int rbase = row0 + wm * 64 + m * 16 + (lane >> 4) * 4;
#pragma unroll
        for (int n = 0; n < 8; n++) {
            int cg = wn * 128 + n * 16 + (lane & 15);
#pragma unroll
            for (int r = 0; r < 4; r++) {
                int rg = rbase + r;
                if (rg < B_N) {
                    float v = acc[m][n][r];
                    msg_out[(size_t)rg * HID + cg] = f2b(v > 0.f ? v : 0.f);
                }
            }
        }
    }
#undef LOAD_A_DELTA
#undef LOAD_A_FB
#undef LOAD_B
#undef WRITE_A_DELTA
#undef WRITE_A_FB
#undef WRITE_B
#undef COMPUTE
}

// ---------------- GEMM 3: atom_hiddens = relu(concat(f_atoms, amsg) @ W_o + b_o) ----------------
__global__ __launch_bounds__(256) void k_gemm_wo(
    const float* __restrict__ fa, const unsigned short* __restrict__ amsg,
    const unsigned short* __restrict__ WoT, const float* __restrict__ bo,
    float* __restrict__ ah)
{
    __shared__ unsigned short As[128][32];
    __shared__ unsigned short Bs[128][32];
    const int bm = blockIdx.y, bn = blockIdx.x;
    const int row0 = bm * 128, col0 = bn * 128;
    const int tid = threadIdx.x, lane = tid & 63, wid = tid >> 6;
    const int wm = wid >> 1, wn = wid & 1;
    const int r0 = tid >> 2, c0 = tid & 3, r1 = 64 + r0;
    const int wsw = (c0 ^ ((r0 >> 1) & 3)) * 8;
    const int rsw = ((lane >> 4) ^ (((lane & 15) >> 1) & 3)) * 8;
    f32x4 acc[4][4] = {};

    const int rg0 = min(row0 + r0, A_N - 1), rg1 = min(row0 + r1, A_N - 1);
    const float* pf0 = fa + (size_t)rg0 * AFD;
    const float* pf1 = fa + (size_t)rg1 * AFD;
    const unsigned short* pm0 = amsg + (size_t)rg0 * HID;
    const unsigned short* pm1 = amsg + (size_t)rg1 * HID;

    for (int k0 = 0; k0 < 672; k0 += 32) {
        __syncthreads();
        if (k0 < 160) {
            int kb = k0 + c0 * 8;
            uint4 q; float v[8];
#pragma unroll
            for (int i = 0; i < 8; i++) { int kg = kb + i; v[i] = (kg < AFD) ? pf0[kg] : 0.f; }
            q.x = pack2f(v[0], v[1]); q.y = pack2f(v[2], v[3]); q.z = pack2f(v[4], v[5]); q.w = pack2f(v[6], v[7]);
            *(uint4*)&As[r0][wsw] = q;
#pragma unroll
            for (int i = 0; i < 8; i++) { int kg = kb + i; v[i] = (kg < AFD) ? pf1[kg] : 0.f; }
            q.x = pack2f(v[0], v[1]); q.y = pack2f(v[2], v[3]); q.z = pack2f(v[4], v[5]); q.w = pack2f(v[6], v[7]);
            *(uint4*)&As[r1][wsw] = q;
        } else {
            int kb = (k0 - 160) + c0 * 8;
            *(uint4*)&As[r0][wsw] = *(const uint4*)(pm0 + kb);
            *(uint4*)&As[r1][wsw] = *(const uint4*)(pm1 + kb);
        }
        *(uint4*)&Bs[r0][wsw] = *(const uint4*)(WoT + (size_t)(col0 + r0) * 672 + k0 + c0 * 8);
        *(uint4*)&Bs[r1][wsw] = *(const uint4*)(WoT + (size_t)(col0 + r1) * 672 + k0 + c0 * 8);
        __syncthreads();

        bf16x8 af[4], bfr[4];
#pragma unroll
        for (int m = 0; m < 4; m++) af[m] = *(const bf16x8*)&As[wm * 64 + m * 16 + (lane & 15)][rsw];
#pragma unroll
        for (int n = 0; n < 4; n++) bfr[n] = *(const bf16x8*)&Bs[wn * 64 + n * 16 + (lane & 15)][rsw];
#pragma unroll
        for (int m = 0; m < 4; m++)
#pragma unroll
            for (int n = 0; n < 4; n++)
                acc[m][n] = __builtin_amdgcn_mfma_f32_16x16x32_bf16(af[m], bfr[n], acc[m][n], 0, 0, 0);
    }

#pragma unroll
    for (int m = 0; m < 4; m++) {
        int rbase = row0 + wm * 64 + m * 16 + (lane >> 4) * 4;
#pragma unroll
        for (int n = 0; n < 4; n++) {
            int cg = col0 + wn * 64 + n * 16 + (lane & 15);
            float bias = bo[cg];
#pragma unroll
            for (int r = 0; r < 4; r++) {
                int rg = rbase + r;
                if (rg < A_N) {
                    float v = acc[m][n][r] + bias;
                    ah[(size_t)rg * HID + cg] = v > 0.f ? v : 0.f;
                }
            }
        }
    }
}

// ---------------- final gather-sum: amsg[a] = sum_k msg[a2b[a][k]] ----------------
__global__ __launch_bounds__(256) void k_gather(
    const unsigned short* __restrict__ msg, const int* __restrict__ a2b,
    unsigned short* __restrict__ amsg)
{
    int g = blockIdx.x * 4 + (threadIdx.x >> 6);
    if (g >= A_N) return;
    int lane = threadIdx.x & 63;
    const int* nb = a2b + (size_t)g * MAXNB;
    float acc[8] = {};
#pragma unroll
    for (int k = 0; k < MAXNB; k++) {
        uint4 v = *(const uint4*)(msg + (size_t)nb[k] * HID + lane * 8);
        acc[0] += blo(v.x); acc[1] += bhi(v.x);
        acc[2] += blo(v.y); acc[3] += bhi(v.y);
        acc[4] += blo(v.z); acc[5] += bhi(v.z);
        acc[6] += blo(v.w); acc[7] += bhi(v.w);
    }
    uint4 q;
    q.x = pack2f(acc[0], acc[1]); q.y = pack2f(acc[2], acc[3]);
    q.z = pack2f(acc[4], acc[5]); q.w = pack2f(acc[6], acc[7]);
    *(uint4*)(amsg + (size_t)g * HID + lane * 8) = q;
}

// ---------------- per-molecule mean (atom_to_mol is sorted) ----------------
__global__ __launch_bounds__(256) void k_segmean(
    const float* __restrict__ ah, const int* __restrict__ a2m, float* __restrict__ out)
{
    int mol = blockIdx.x, t = threadIdx.x;
    int lo, hi;
    { int l = 0, r = A_N; while (l < r) { int m = (l + r) >> 1; if (a2m[m] < mol) l = m + 1; else r = m; } lo = l; }
    { int l = lo, r = A_N; while (l < r) { int m = (l + r) >> 1; if (a2m[m] < mol + 1) l = m + 1; else r = m; } hi = l; }
    float s0 = 0.f, s1 = 0.f;
    for (int a = lo; a < hi; a++) {
        s0 += ah[(size_t)a * HID + t];
        s1 += ah[(size_t)a * HID + 256 + t];
    }
    int c = hi - lo;
    float inv = c > 0 ? 1.0f / (float)c : 0.f;
    out[(size_t)mol * HID + t] = s0 * inv;
    out[(size_t)mol * HID + 256 + t] = s1 * inv;
}

extern "C" void kernel_launch(void* const* d_in, const int* in_sizes, int n_in,
                              void* d_out, int out_size, void* d_ws, size_t ws_size,
                              hipStream_t stream)
{
    const float* f_atoms = (const float*)d_in[0];
    const float* f_bonds = (const float*)d_in[1];
    const float* W_i     = (const float*)d_in[2];
    const float* W_h     = (const float*)d_in[3];
    const float* W_o     = (const float*)d_in[4];
    const float* b_o     = (const float*)d_in[5];
    const int*   a2b     = (const int*)d_in[6];
    const int*   b2a     = (const int*)d_in[7];
    const int*   b2revb  = (const int*)d_in[8];
    const int*   a2m     = (const int*)d_in[9];

    // workspace layout: 411,140,096 bytes (known budget ~432 MiB)
    const size_t OFF_MSGA = 0;              // bf16 [B,H] ; later f32 ah [A,H]
    const size_t OFF_MSGB = 204800000;      // bf16 [B,H] ; later bf16 amsg [A,H]
    const size_t OFF_WIT  = 409600000;      // 163,840
    const size_t OFF_WCAT = 409763840;      // 688,128 (tile-major)
    const size_t OFF_WOT  = 410451968;      // 688,128
    const size_t REQUIRED = 411140096;

    if (ws_size < REQUIRED) {
        float val = -(10000.0f + (float)(ws_size >> 20));
        k_diag<<<dim3((out_size + 255) / 256), dim3(256), 0, stream>>>((float*)d_out, out_size, val);
        return;
    }

    char* w = (char*)d_ws;
    unsigned short* msgA  = (unsigned short*)(w + OFF_MSGA);
    unsigned short* msgB  = (unsigned short*)(w + OFF_MSGB);
    unsigned short* WiT   = (unsigned short*)(w + OFF_WIT);
    unsigned short* WcatB = (unsigned short*)(w + OFF_WCAT);
    unsigned short* WoT   = (unsigned short*)(w + OFF_WOT);
    unsigned short* amsg  = (unsigned short*)(w + OFF_MSGB);  // aliases msgB (dead after loop)
    float* ah             = (float*)(w + OFF_MSGA);           // aliases msgA (dead after gather)

    k_weights<<<dim3(512), dim3(256), 0, stream>>>(W_i, W_h, W_o, WiT, WcatB, WoT);
    k_gemm_wi<<<dim3(4, 1563), dim3(256), 0, stream>>>(f_bonds, WiT, msgA);
    for (int it = 0; it < 4; ++it) {
        const unsigned short* mi = (it & 1) ? msgB : msgA;
        unsigned short*       mo = (it & 1) ? msgA : msgB;
        k_gemm_wh_fused<<<dim3(1563), dim3(512), 0, stream>>>(f_bonds, mi, WcatB, a2b, b2a, b2revb, mo);
    }
    k_gather<<<dim3(25000), dim3(256), 0, stream>>>(msgA, a2b, amsg);
    k_gemm_wo<<<dim3(4, 782), dim3(256), 0, stream>>>(f_atoms, amsg, WoT, b_o, ah);
    k_segmean<<<dim3(NMOL), dim3(256), 0, stream>>>(ah, a2m, (float*)d_out);
}

// Round 5
// 2447.726 us; speedup vs baseline: 1.5344x; 1.5344x over previous
//
#include <hip/hip_runtime.h>
#include <hip/hip_bf16.h>
#include <cstdint>

#define A_N   100000   // atoms
#define B_N   200000   // bonds
#define MAXNB 6
#define AFD   133
#define BFD   147
#define HID   512
#define NMOL  8192

typedef __attribute__((ext_vector_type(8))) short bf16x8;
typedef __attribute__((ext_vector_type(4))) float f32x4;

__device__ __forceinline__ unsigned short f2b(float f) {
    unsigned u = __builtin_bit_cast(unsigned, f);
    u += 0x7fffu + ((u >> 16) & 1u);
    return (unsigned short)(u >> 16);
}
__device__ __forceinline__ float blo(unsigned u) { return __builtin_bit_cast(float, u << 16); }
__device__ __forceinline__ float bhi(unsigned u) { return __builtin_bit_cast(float, u & 0xffff0000u); }
__device__ __forceinline__ unsigned pack2f(float a, float b) {
    return (unsigned)f2b(a) | ((unsigned)f2b(b) << 16);
}
__device__ __forceinline__ void glds16(const void* g, void* l) {
    __builtin_amdgcn_global_load_lds((const __attribute__((address_space(1))) unsigned*)g,
                                     (__attribute__((address_space(3))) unsigned*)l, 16, 0, 0);
}

// ---------------- diagnostic fallback (ws too small) ----------------
__global__ __launch_bounds__(256) void k_diag(float* __restrict__ out, int n, float val) {
    int i = blockIdx.x * 256 + threadIdx.x;
    if (i < n) out[i] = val;
}

// ---------------- weight transpose + cast ----------------
// WiT[n][k]   : k 0..146 = Wi[k][n], 147..159 = 0                          (512 x 160 row-major)
// WcatImg     : pre-swizzled LDS image, tile (bn*21+kt) = 4096 ush; logical k: 0..511 Wh, 512..658 Wi, 659.. 0
// WoT[n][k]   : k 0..132 = Wo[k][n], 133..159 = 0, 160..671 = Wo[k-27][n]  (512 x 672 row-major)
__global__ __launch_bounds__(256) void k_weights(
    const float* __restrict__ Wi, const float* __restrict__ Wh, const float* __restrict__ Wo,
    unsigned short* __restrict__ WiT, unsigned short* __restrict__ WcatImg, unsigned short* __restrict__ WoT)
{
    int n = blockIdx.x, t = threadIdx.x;
    for (int k = t; k < 160; k += 256)
        WiT[(size_t)n * 160 + k] = (k < BFD) ? f2b(Wi[(size_t)k * HID + n]) : (unsigned short)0;
    for (int k = t; k < 672; k += 256) {
        unsigned short v;
        if (k < HID)             v = f2b(Wh[(size_t)k * HID + n]);
        else if (k < HID + BFD)  v = f2b(Wi[(size_t)(k - HID) * HID + n]);
        else                     v = 0;
        int row = n & 127;
        size_t tile = (size_t)(n >> 7) * 21 + (k >> 5);
        WcatImg[tile * 4096 + row * 32 + ((((k >> 3) & 3) ^ ((row >> 1) & 3)) << 3) + (k & 7)] = v;
    }
    for (int k = t; k < 672; k += 256) {
        unsigned short v;
        if (k < AFD)       v = f2b(Wo[(size_t)k * HID + n]);
        else if (k < 160)  v = 0;
        else               v = f2b(Wo[(size_t)(k - 27) * HID + n]);
        WoT[(size_t)n * 672 + k] = v;
    }
}

// ---------------- GEMM 1: msg = relu(f_bonds @ W_i) ----------------
__global__ __launch_bounds__(256) void k_gemm_wi(
    const float* __restrict__ fb, const unsigned short* __restrict__ WiT,
    unsigned short* __restrict__ msg)
{
    __shared__ unsigned short As[128][32];
    __shared__ unsigned short Bs[128][32];
    // XCD-chunked bijective remap: nwg = 6252 = 8*781 + 4
    const int orig = blockIdx.x;
    const int xcd = orig & 7, idx = orig >> 3;
    const int wg = (xcd < 4 ? xcd * 782 : 3128 + (xcd - 4) * 781) + idx;
    const int bm = wg >> 2, bn = wg & 3;
    const int row0 = bm * 128, col0 = bn * 128;

    const int tid = threadIdx.x, lane = tid & 63, wid = tid >> 6;
    const int wm = wid >> 1, wn = wid & 1;
    const int r0 = tid >> 2, c0 = tid & 3, r1 = 64 + r0;
    const int wsw = (c0 ^ ((r0 >> 1) & 3)) * 8;
    const int rsw = ((lane >> 4) ^ (((lane & 15) >> 1) & 3)) * 8;
    f32x4 acc[4][4] = {};

    const float* pf0 = fb + (size_t)min(row0 + r0, B_N - 1) * BFD;
    const float* pf1 = fb + (size_t)min(row0 + r1, B_N - 1) * BFD;
    const unsigned short* pb0 = WiT + (size_t)(col0 + r0) * 160;
    const unsigned short* pb1 = WiT + (size_t)(col0 + r1) * 160;

    float v0[8], v1[8];
    uint4 b0, b1;

#define LOADA(kt) do { int kb = (kt) * 32 + c0 * 8; \
        _Pragma("unroll") for (int i = 0; i < 8; i++) { int kg = kb + i; v0[i] = (kg < BFD) ? pf0[kg] : 0.f; } \
        _Pragma("unroll") for (int i = 0; i < 8; i++) { int kg = kb + i; v1[i] = (kg < BFD) ? pf1[kg] : 0.f; } } while (0)
#define LOADB(kt) do { int kb = (kt) * 32 + c0 * 8; \
        b0 = *(const uint4*)(pb0 + kb); b1 = *(const uint4*)(pb1 + kb); } while (0)

    LOADA(0); LOADB(0);
    for (int kt = 0; kt < 5; ++kt) {
        __syncthreads();
        uint4 q;
        q.x = pack2f(v0[0], v0[1]); q.y = pack2f(v0[2], v0[3]); q.z = pack2f(v0[4], v0[5]); q.w = pack2f(v0[6], v0[7]);
        *(uint4*)&As[r0][wsw] = q;
        q.x = pack2f(v1[0], v1[1]); q.y = pack2f(v1[2], v1[3]); q.z = pack2f(v1[4], v1[5]); q.w = pack2f(v1[6], v1[7]);
        *(uint4*)&As[r1][wsw] = q;
        *(uint4*)&Bs[r0][wsw] = b0;
        *(uint4*)&Bs[r1][wsw] = b1;
        __syncthreads();
        if (kt < 4) { LOADA(kt + 1); LOADB(kt + 1); }

        bf16x8 af[4], bfr[4];
#pragma unroll
        for (int m = 0; m < 4; m++) af[m] = *(const bf16x8*)&As[wm * 64 + m * 16 + (lane & 15)][rsw];
#pragma unroll
        for (int n = 0; n < 4; n++) bfr[n] = *(const bf16x8*)&Bs[wn * 64 + n * 16 + (lane & 15)][rsw];
#pragma unroll
        for (int m = 0; m < 4; m++)
#pragma unroll
            for (int n = 0; n < 4; n++)
                acc[m][n] = __builtin_amdgcn_mfma_f32_16x16x32_bf16(af[m], bfr[n], acc[m][n], 0, 0, 0);
    }
#undef LOADA
#undef LOADB

#pragma unroll
    for (int m = 0; m < 4; m++) {
        int rbase = row0 + wm * 64 + m * 16 + (lane >> 4) * 4;
#pragma unroll
        for (int n = 0; n < 4; n++) {
            int cg = col0 + wn * 64 + n * 16 + (lane & 15);
#pragma unroll
            for (int r = 0; r < 4; r++) {
                int rg = rbase + r;
                if (rg < B_N) {
                    float v = acc[m][n][r];
                    msg[(size_t)rg * HID + cg] = f2b(v > 0.f ? v : 0.f);
                }
            }
        }
    }
}

// ---------------- delta: D[b] = sum_k msg[a2b[b2a[b]][k]] - msg[b2revb[b]] ----------------
__global__ __launch_bounds__(256) void k_delta(
    const unsigned short* __restrict__ msg, const int* __restrict__ a2b,
    const int* __restrict__ b2a, const int* __restrict__ b2revb,
    unsigned short* __restrict__ D)
{
    int b = blockIdx.x * 4 + (threadIdx.x >> 6);
    if (b >= B_N) return;
    int lane = threadIdx.x & 63;
    const int atom = b2a[b];
    const int rev  = b2revb[b];
    const int* nb = a2b + (size_t)atom * MAXNB;
    float acc[8];
    {
        uint4 v = *(const uint4*)(msg + (size_t)rev * HID + lane * 8);
        acc[0] = -blo(v.x); acc[1] = -bhi(v.x);
        acc[2] = -blo(v.y); acc[3] = -bhi(v.y);
        acc[4] = -blo(v.z); acc[5] = -bhi(v.z);
        acc[6] = -blo(v.w); acc[7] = -bhi(v.w);
    }
#pragma unroll
    for (int k = 0; k < MAXNB; k++) {
        uint4 v = *(const uint4*)(msg + (size_t)nb[k] * HID + lane * 8);
        acc[0] += blo(v.x); acc[1] += bhi(v.x);
        acc[2] += blo(v.y); acc[3] += bhi(v.y);
        acc[4] += blo(v.z); acc[5] += bhi(v.z);
        acc[6] += blo(v.w); acc[7] += bhi(v.w);
    }
    uint4 q;
    q.x = pack2f(acc[0], acc[1]); q.y = pack2f(acc[2], acc[3]);
    q.z = pack2f(acc[4], acc[5]); q.w = pack2f(acc[6], acc[7]);
    *(uint4*)(D + (size_t)b * HID + lane * 8) = q;
}

// ---------------- GEMM 2 (hot): msg = relu([D | f_bonds] @ [W_h; W_i]) ----------------
// B staged via global_load_lds from pre-swizzled WcatImg (double-buffered); A reg-prefetched.
__global__ __launch_bounds__(256) void k_gemm_wh(
    const unsigned short* __restrict__ D, const float* __restrict__ fb,
    const unsigned short* __restrict__ WcatImg,
    unsigned short* __restrict__ msg_out)
{
    __shared__ unsigned short As[128][32];
    __shared__ unsigned short Bs[2][4096];
    const int orig = blockIdx.x;
    const int xcd = orig & 7, idx = orig >> 3;
    const int wg = (xcd < 4 ? xcd * 782 : 3128 + (xcd - 4) * 781) + idx;
    const int bm = wg >> 2, bn = wg & 3;
    const int row0 = bm * 128;

    const int tid = threadIdx.x, lane = tid & 63, wid = tid >> 6;
    const int wm = wid >> 1, wn = wid & 1;
    const int r0 = tid >> 2, c0 = tid & 3, r1 = 64 + r0;
    const int wsw = (c0 ^ ((r0 >> 1) & 3)) * 8;
    const int rsw = ((lane >> 4) ^ (((lane & 15) >> 1) & 3)) * 8;
    f32x4 acc[4][4] = {};

    const int rg0 = min(row0 + r0, B_N - 1), rg1 = min(row0 + r1, B_N - 1);
    const unsigned short* pd0 = D + (size_t)rg0 * HID;
    const unsigned short* pd1 = D + (size_t)rg1 * HID;
    const float* pf0 = fb + (size_t)rg0 * BFD;
    const float* pf1 = fb + (size_t)rg1 * BFD;
    const char* img = (const char*)WcatImg + (size_t)bn * 21 * 8192;
    char* bsb = (char*)&Bs[0][0] + wid * 2048;

    uint4 a0, a1;
    float v0[8], v1[8];

#define GLDSB(kt, buf) do { \
        const char* s = img + (size_t)(kt) * 8192 + wid * 2048 + lane * 16; \
        char* d = bsb + (buf) * 8192; \
        glds16(s, d); \
        glds16(s + 1024, d + 1024); } while (0)
#define LOADA_D(kt) do { int kb = (kt) * 32 + c0 * 8; \
        a0 = *(const uint4*)(pd0 + kb); a1 = *(const uint4*)(pd1 + kb); } while (0)
#define LOADA_F(kt) do { int kb = (kt) * 32 - HID + c0 * 8; \
        _Pragma("unroll") for (int i = 0; i < 8; i++) { int kg = kb + i; v0[i] = (kg < BFD) ? pf0[kg] : 0.f; } \
        _Pragma("unroll") for (int i = 0; i < 8; i++) { int kg = kb + i; v1[i] = (kg < BFD) ? pf1[kg] : 0.f; } } while (0)

    GLDSB(0, 0);
    LOADA_D(0);
    for (int kt = 0; kt < 21; ++kt) {
        __syncthreads();                   // drains glds B(kt) + A regs; prev compute done
        if (kt < 16) {
            *(uint4*)&As[r0][wsw] = a0;
            *(uint4*)&As[r1][wsw] = a1;
        } else {
            uint4 q;
            q.x = pack2f(v0[0], v0[1]); q.y = pack2f(v0[2], v0[3]); q.z = pack2f(v0[4], v0[5]); q.w = pack2f(v0[6], v0[7]);
            *(uint4*)&As[r0][wsw] = q;
            q.x = pack2f(v1[0], v1[1]); q.y = pack2f(v1[2], v1[3]); q.z = pack2f(v1[4], v1[5]); q.w = pack2f(v1[6], v1[7]);
            *(uint4*)&As[r1][wsw] = q;
        }
        __syncthreads();                   // A tile visible
        if (kt < 20) {                     // issue next-step loads; overlap with compute below
            GLDSB(kt + 1, (kt + 1) & 1);
            if (kt + 1 < 16) LOADA_D(kt + 1); else LOADA_F(kt + 1);
        }
        bf16x8 af[4], bfr[4];
#pragma unroll
        for (int m = 0; m < 4; m++) af[m] = *(const bf16x8*)&As[wm * 64 + m * 16 + (lane & 15)][rsw];
#pragma unroll
        for (int n = 0; n < 4; n++) bfr[n] = *(const bf16x8*)&Bs[kt & 1][(wn * 64 + n * 16 + (lane & 15)) * 32 + rsw];
#pragma unroll
        for (int m = 0; m < 4; m++)
#pragma unroll
            for (int n = 0; n < 4; n++)
                acc[m][n] = __builtin_amdgcn_mfma_f32_16x16x32_bf16(af[m], bfr[n], acc[m][n], 0, 0, 0);
    }
#undef GLDSB
#undef LOADA_D
#undef LOADA_F

#pragma unroll
    for (int m = 0; m < 4; m++) {
        int rbase = row0 + wm * 64 + m * 16 + (lane >> 4) * 4;
#pragma unroll
        for (int n = 0; n < 4; n++) {
            int cg = bn * 128 + wn * 64 + n * 16 + (lane & 15);
#pragma unroll
            for (int r = 0; r < 4; r++) {
                int rg = rbase + r;
                if (rg < B_N) {
                    float v = acc[m][n][r];
                    msg_out[(size_t)rg * HID + cg] = f2b(v > 0.f ? v : 0.f);
                }
            }
        }
    }
}

// ---------------- GEMM 3: atom_hiddens = relu(concat(f_atoms, amsg) @ W_o + b_o) ----------------
__global__ __launch_bounds__(256) void k_gemm_wo(
    const float* __restrict__ fa, const unsigned short* __restrict__ amsg,
    const unsigned short* __restrict__ WoT, const float* __restrict__ bo,
    float* __restrict__ ah)
{
    __shared__ unsigned short As[128][32];
    __shared__ unsigned short Bs[128][32];
    // nwg = 3128 = 8 * 391
    const int orig = blockIdx.x;
    const int wg = (orig & 7) * 391 + (orig >> 3);
    const int bm = wg >> 2, bn = wg & 3;
    const int row0 = bm * 128, col0 = bn * 128;

    const int tid = threadIdx.x, lane = tid & 63, wid = tid >> 6;
    const int wm = wid >> 1, wn = wid & 1;
    const int r0 = tid >> 2, c0 = tid & 3, r1 = 64 + r0;
    const int wsw = (c0 ^ ((r0 >> 1) & 3)) * 8;
    const int rsw = ((lane >> 4) ^ (((lane & 15) >> 1) & 3)) * 8;
    f32x4 acc[4][4] = {};

    const int rg0 = min(row0 + r0, A_N - 1), rg1 = min(row0 + r1, A_N - 1);
    const float* pf0 = fa + (size_t)rg0 * AFD;
    const float* pf1 = fa + (size_t)rg1 * AFD;
    const unsigned short* pm0 = amsg + (size_t)rg0 * HID;
    const unsigned short* pm1 = amsg + (size_t)rg1 * HID;
    const unsigned short* pb0 = WoT + (size_t)(col0 + r0) * 672;
    const unsigned short* pb1 = WoT + (size_t)(col0 + r1) * 672;

    uint4 a0, a1, b0, b1;
    float v0[8], v1[8];

#define LOADA(kt) do { \
        if ((kt) < 5) { int kb = (kt) * 32 + c0 * 8; \
            _Pragma("unroll") for (int i = 0; i < 8; i++) { int kg = kb + i; v0[i] = (kg < AFD) ? pf0[kg] : 0.f; } \
            _Pragma("unroll") for (int i = 0; i < 8; i++) { int kg = kb + i; v1[i] = (kg < AFD) ? pf1[kg] : 0.f; } \
        } else { int kb = (kt) * 32 - 160 + c0 * 8; \
            a0 = *(const uint4*)(pm0 + kb); a1 = *(const uint4*)(pm1 + kb); } } while (0)
#define LOADB(kt) do { int kb = (kt) * 32 + c0 * 8; \
        b0 = *(const uint4*)(pb0 + kb); b1 = *(const uint4*)(pb1 + kb); } while (0)

    LOADA(0); LOADB(0);
    for (int kt = 0; kt < 21; ++kt) {
        __syncthreads();
        if (kt < 5) {
            uint4 q;
            q.x = pack2f(v0[0], v0[1]); q.y = pack2f(v0[2], v0[3]); q.z = pack2f(v0[4], v0[5]); q.w = pack2f(v0[6], v0[7]);
            *(uint4*)&As[r0][wsw] = q;
            q.x = pack2f(v1[0], v1[1]); q.y = pack2f(v1[2], v1[3]); q.z = pack2f(v1[4], v1[5]); q.w = pack2f(v1[6], v1[7]);
            *(uint4*)&As[r1][wsw] = q;
        } else {
            *(uint4*)&As[r0][wsw] = a0;
            *(uint4*)&As[r1][wsw] = a1;
        }
        *(uint4*)&Bs[r0][wsw] = b0;
        *(uint4*)&Bs[r1][wsw] = b1;
        __syncthreads();
        if (kt < 20) { LOADA(kt + 1); LOADB(kt + 1); }

        bf16x8 af[4], bfr[4];
#pragma unroll
        for (int m = 0; m < 4; m++) af[m] = *(const bf16x8*)&As[wm * 64 + m * 16 + (lane & 15)][rsw];
#pragma unroll
        for (int n = 0; n < 4; n++) bfr[n] = *(const bf16x8*)&Bs[wn * 64 + n * 16 + (lane & 15)][rsw];
#pragma unroll
        for (int m = 0; m < 4; m++)
#pragma unroll
            for (int n = 0; n < 4; n++)
                acc[m][n] = __builtin_amdgcn_mfma_f32_16x16x32_bf16(af[m], bfr[n], acc[m][n], 0, 0, 0);
    }
#undef LOADA
#undef LOADB

#pragma unroll
    for (int m = 0; m < 4; m++) {
        int rbase = row0 + wm * 64 + m * 16 + (lane >> 4) * 4;
#pragma unroll
        for (int n = 0; n < 4; n++) {
            int cg = col0 + wn * 64 + n * 16 + (lane & 15);
            float bias = bo[cg];
#pragma unroll
            for (int r = 0; r < 4; r++) {
                int rg = rbase + r;
                if (rg < A_N) {
                    float v = acc[m][n][r] + bias;
                    ah[(size_t)rg * HID + cg] = v > 0.f ? v : 0.f;
                }
            }
        }
    }
}

// ---------------- final gather-sum: amsg[a] = sum_k msg[a2b[a][k]] ----------------
__global__ __launch_bounds__(256) void k_gather(
    const unsigned short* __restrict__ msg, const int* __restrict__ a2b,
    unsigned short* __restrict__ amsg)
{
    int g = blockIdx.x * 4 + (threadIdx.x >> 6);
    if (g >= A_N) return;
    int lane = threadIdx.x & 63;
    const int* nb = a2b + (size_t)g * MAXNB;
    float acc[8] = {};
#pragma unroll
    for (int k = 0; k < MAXNB; k++) {
        uint4 v = *(const uint4*)(msg + (size_t)nb[k] * HID + lane * 8);
        acc[0] += blo(v.x); acc[1] += bhi(v.x);
        acc[2] += blo(v.y); acc[3] += bhi(v.y);
        acc[4] += blo(v.z); acc[5] += bhi(v.z);
        acc[6] += blo(v.w); acc[7] += bhi(v.w);
    }
    uint4 q;
    q.x = pack2f(acc[0], acc[1]); q.y = pack2f(acc[2], acc[3]);
    q.z = pack2f(acc[4], acc[5]); q.w = pack2f(acc[6], acc[7]);
    *(uint4*)(amsg + (size_t)g * HID + lane * 8) = q;
}

// ---------------- per-molecule mean (atom_to_mol is sorted) ----------------
__global__ __launch_bounds__(256) void k_segmean(
    const float* __restrict__ ah, const int* __restrict__ a2m, float* __restrict__ out)
{
    int mol = blockIdx.x, t = threadIdx.x;
    int lo, hi;
    { int l = 0, r = A_N; while (l < r) { int m = (l + r) >> 1; if (a2m[m] < mol) l = m + 1; else r = m; } lo = l; }
    { int l = lo, r = A_N; while (l < r) { int m = (l + r) >> 1; if (a2m[m] < mol + 1) l = m + 1; else r = m; } hi = l; }
    float s0 = 0.f, s1 = 0.f;
    for (int a = lo; a < hi; a++) {
        s0 += ah[(size_t)a * HID + t];
        s1 += ah[(size_t)a * HID + 256 + t];
    }
    int c = hi - lo;
    float inv = c > 0 ? 1.0f / (float)c : 0.f;
    out[(size_t)mol * HID + t] = s0 * inv;
    out[(size_t)mol * HID + 256 + t] = s1 * inv;
}

extern "C" void kernel_launch(void* const* d_in, const int* in_sizes, int n_in,
                              void* d_out, int out_size, void* d_ws, size_t ws_size,
                              hipStream_t stream)
{
    const float* f_atoms = (const float*)d_in[0];
    const float* f_bonds = (const float*)d_in[1];
    const float* W_i     = (const float*)d_in[2];
    const float* W_h     = (const float*)d_in[3];
    const float* W_o     = (const float*)d_in[4];
    const float* b_o     = (const float*)d_in[5];
    const int*   a2b     = (const int*)d_in[6];
    const int*   b2a     = (const int*)d_in[7];
    const int*   b2revb  = (const int*)d_in[8];
    const int*   a2m     = (const int*)d_in[9];

    const size_t OFF_MSG  = 0;              // bf16 [B,H] ; later f32 ah [A,H]
    const size_t OFF_D    = 204800000;      // bf16 [B,H] ; later bf16 amsg [A,H]
    const size_t OFF_WIT  = 409600000;      // 163,840
    const size_t OFF_WCAT = 409763840;      // 688,128 (pre-swizzled image)
    const size_t OFF_WOT  = 410451968;      // 688,128
    const size_t REQUIRED = 411140096;

    if (ws_size < REQUIRED) {
        float val = -(10000.0f + (float)(ws_size >> 20));
        k_diag<<<dim3((out_size + 255) / 256), dim3(256), 0, stream>>>((float*)d_out, out_size, val);
        return;
    }

    char* w = (char*)d_ws;
    unsigned short* msg   = (unsigned short*)(w + OFF_MSG);
    unsigned short* D     = (unsigned short*)(w + OFF_D);
    unsigned short* amsg  = (unsigned short*)(w + OFF_D);   // aliases D (dead after loop)
    unsigned short* WiT   = (unsigned short*)(w + OFF_WIT);
    unsigned short* Wcat  = (unsigned short*)(w + OFF_WCAT);
    unsigned short* WoT   = (unsigned short*)(w + OFF_WOT);
    float* ah             = (float*)(w + OFF_MSG);          // aliases msg (dead after gather)

    k_weights<<<dim3(512), dim3(256), 0, stream>>>(W_i, W_h, W_o, WiT, Wcat, WoT);
    k_gemm_wi<<<dim3(6252), dim3(256), 0, stream>>>(f_bonds, WiT, msg);
    for (int it = 0; it < 4; ++it) {
        k_delta<<<dim3(50000), dim3(256), 0, stream>>>(msg, a2b, b2a, b2revb, D);
        k_gemm_wh<<<dim3(6252), dim3(256), 0, stream>>>(D, f_bonds, Wcat, msg);
    }
    k_gather<<<dim3(25000), dim3(256), 0, stream>>>(msg, a2b, amsg);
    k_gemm_wo<<<dim3(3128), dim3(256), 0, stream>>>(f_atoms, amsg, WoT, b_o, ah);
    k_segmean<<<dim3(NMOL), dim3(256), 0, stream>>>(ah, a2m, (float*)d_out);
}

// Round 6
// 2383.766 us; speedup vs baseline: 1.5755x; 1.0268x over previous
//
#include <hip/hip_runtime.h>
#include <hip/hip_bf16.h>
#include <cstdint>

#define A_N   100000   // atoms
#define B_N   200000   // bonds
#define MAXNB 6
#define AFD   133
#define BFD   147
#define HID   512
#define NMOL  8192

typedef __attribute__((ext_vector_type(8))) short bf16x8;
typedef __attribute__((ext_vector_type(4))) float f32x4;

__device__ __forceinline__ unsigned short f2b(float f) {
    unsigned u = __builtin_bit_cast(unsigned, f);
    u += 0x7fffu + ((u >> 16) & 1u);
    return (unsigned short)(u >> 16);
}
__device__ __forceinline__ float blo(unsigned u) { return __builtin_bit_cast(float, u << 16); }
__device__ __forceinline__ float bhi(unsigned u) { return __builtin_bit_cast(float, u & 0xffff0000u); }
__device__ __forceinline__ unsigned pack2f(float a, float b) {
    return (unsigned)f2b(a) | ((unsigned)f2b(b) << 16);
}
__device__ __forceinline__ void glds16(const void* g, void* l) {
    __builtin_amdgcn_global_load_lds((const __attribute__((address_space(1))) unsigned*)g,
                                     (__attribute__((address_space(3))) unsigned*)l, 16, 0, 0);
}

// ---------------- diagnostic fallback (ws too small) ----------------
__global__ __launch_bounds__(256) void k_diag(float* __restrict__ out, int n, float val) {
    int i = blockIdx.x * 256 + threadIdx.x;
    if (i < n) out[i] = val;
}

// ---------------- weight transpose + cast ----------------
// WiT[n][k]   : k 0..146 = Wi[k][n], 147..159 = 0                          (512 x 160 row-major)
// WcatImg     : pre-swizzled LDS image, tile (bn*21+kt) = 4096 ush; logical k: 0..511 Wh, 512..658 Wi, 659.. 0
// WoT[n][k]   : k 0..132 = Wo[k][n], 133..159 = 0, 160..671 = Wo[k-27][n]  (512 x 672 row-major)
__global__ __launch_bounds__(256) void k_weights(
    const float* __restrict__ Wi, const float* __restrict__ Wh, const float* __restrict__ Wo,
    unsigned short* __restrict__ WiT, unsigned short* __restrict__ WcatImg, unsigned short* __restrict__ WoT)
{
    int n = blockIdx.x, t = threadIdx.x;
    for (int k = t; k < 160; k += 256)
        WiT[(size_t)n * 160 + k] = (k < BFD) ? f2b(Wi[(size_t)k * HID + n]) : (unsigned short)0;
    for (int k = t; k < 672; k += 256) {
        unsigned short v;
        if (k < HID)             v = f2b(Wh[(size_t)k * HID + n]);
        else if (k < HID + BFD)  v = f2b(Wi[(size_t)(k - HID) * HID + n]);
        else                     v = 0;
        int row = n & 127;
        size_t tile = (size_t)(n >> 7) * 21 + (k >> 5);
        WcatImg[tile * 4096 + row * 32 + ((((k >> 3) & 3) ^ ((row >> 1) & 3)) << 3) + (k & 7)] = v;
    }
    for (int k = t; k < 672; k += 256) {
        unsigned short v;
        if (k < AFD)       v = f2b(Wo[(size_t)k * HID + n]);
        else if (k < 160)  v = 0;
        else               v = f2b(Wo[(size_t)(k - 27) * HID + n]);
        WoT[(size_t)n * 672 + k] = v;
    }
}

// ---------------- GEMM 1: msg = relu(f_bonds @ W_i) ----------------
__global__ __launch_bounds__(256) void k_gemm_wi(
    const float* __restrict__ fb, const unsigned short* __restrict__ WiT,
    unsigned short* __restrict__ msg)
{
    __shared__ unsigned short As[128][32];
    __shared__ unsigned short Bs[128][32];
    const int orig = blockIdx.x;
    const int xcd = orig & 7, idx = orig >> 3;
    const int wg = (xcd < 4 ? xcd * 782 : 3128 + (xcd - 4) * 781) + idx;
    const int bm = wg >> 2, bn = wg & 3;
    const int row0 = bm * 128, col0 = bn * 128;

    const int tid = threadIdx.x, lane = tid & 63, wid = tid >> 6;
    const int wm = wid >> 1, wn = wid & 1;
    const int r0 = tid >> 2, c0 = tid & 3, r1 = 64 + r0;
    const int wsw = (c0 ^ ((r0 >> 1) & 3)) * 8;
    const int rsw = ((lane >> 4) ^ (((lane & 15) >> 1) & 3)) * 8;
    f32x4 acc[4][4] = {};

    const float* pf0 = fb + (size_t)min(row0 + r0, B_N - 1) * BFD;
    const float* pf1 = fb + (size_t)min(row0 + r1, B_N - 1) * BFD;
    const unsigned short* pb0 = WiT + (size_t)(col0 + r0) * 160;
    const unsigned short* pb1 = WiT + (size_t)(col0 + r1) * 160;

    float v0[8], v1[8];
    uint4 b0, b1;

#define LOADA(kt) do { int kb = (kt) * 32 + c0 * 8; \
        _Pragma("unroll") for (int i = 0; i < 8; i++) { int kg = kb + i; v0[i] = (kg < BFD) ? pf0[kg] : 0.f; } \
        _Pragma("unroll") for (int i = 0; i < 8; i++) { int kg = kb + i; v1[i] = (kg < BFD) ? pf1[kg] : 0.f; } } while (0)
#define LOADB(kt) do { int kb = (kt) * 32 + c0 * 8; \
        b0 = *(const uint4*)(pb0 + kb); b1 = *(const uint4*)(pb1 + kb); } while (0)

    LOADA(0); LOADB(0);
    for (int kt = 0; kt < 5; ++kt) {
        __syncthreads();
        uint4 q;
        q.x = pack2f(v0[0], v0[1]); q.y = pack2f(v0[2], v0[3]); q.z = pack2f(v0[4], v0[5]); q.w = pack2f(v0[6], v0[7]);
        *(uint4*)&As[r0][wsw] = q;
        q.x = pack2f(v1[0], v1[1]); q.y = pack2f(v1[2], v1[3]); q.z = pack2f(v1[4], v1[5]); q.w = pack2f(v1[6], v1[7]);
        *(uint4*)&As[r1][wsw] = q;
        *(uint4*)&Bs[r0][wsw] = b0;
        *(uint4*)&Bs[r1][wsw] = b1;
        __syncthreads();
        if (kt < 4) { LOADA(kt + 1); LOADB(kt + 1); }

        bf16x8 af[4], bfr[4];
#pragma unroll
        for (int m = 0; m < 4; m++) af[m] = *(const bf16x8*)&As[wm * 64 + m * 16 + (lane & 15)][rsw];
#pragma unroll
        for (int n = 0; n < 4; n++) bfr[n] = *(const bf16x8*)&Bs[wn * 64 + n * 16 + (lane & 15)][rsw];
#pragma unroll
        for (int m = 0; m < 4; m++)
#pragma unroll
            for (int n = 0; n < 4; n++)
                acc[m][n] = __builtin_amdgcn_mfma_f32_16x16x32_bf16(af[m], bfr[n], acc[m][n], 0, 0, 0);
    }
#undef LOADA
#undef LOADB

#pragma unroll
    for (int m = 0; m < 4; m++) {
        int rbase = row0 + wm * 64 + m * 16 + (lane >> 4) * 4;
#pragma unroll
        for (int n = 0; n < 4; n++) {
            int cg = col0 + wn * 64 + n * 16 + (lane & 15);
#pragma unroll
            for (int r = 0; r < 4; r++) {
                int rg = rbase + r;
                if (rg < B_N) {
                    float v = acc[m][n][r];
                    msg[(size_t)rg * HID + cg] = f2b(v > 0.f ? v : 0.f);
                }
            }
        }
    }
}

// ---------------- delta: D[b] = sum_k msg[a2b[b2a[b]][k]] - msg[b2revb[b]] ----------------
__global__ __launch_bounds__(256) void k_delta(
    const unsigned short* __restrict__ msg, const int* __restrict__ a2b,
    const int* __restrict__ b2a, const int* __restrict__ b2revb,
    unsigned short* __restrict__ D)
{
    int b = blockIdx.x * 4 + (threadIdx.x >> 6);
    if (b >= B_N) return;
    int lane = threadIdx.x & 63;
    const int atom = b2a[b];
    const int rev  = b2revb[b];
    const int* nb = a2b + (size_t)atom * MAXNB;
    float acc[8];
    {
        uint4 v = *(const uint4*)(msg + (size_t)rev * HID + lane * 8);
        acc[0] = -blo(v.x); acc[1] = -bhi(v.x);
        acc[2] = -blo(v.y); acc[3] = -bhi(v.y);
        acc[4] = -blo(v.z); acc[5] = -bhi(v.z);
        acc[6] = -blo(v.w); acc[7] = -bhi(v.w);
    }
#pragma unroll
    for (int k = 0; k < MAXNB; k++) {
        uint4 v = *(const uint4*)(msg + (size_t)nb[k] * HID + lane * 8);
        acc[0] += blo(v.x); acc[1] += bhi(v.x);
        acc[2] += blo(v.y); acc[3] += bhi(v.y);
        acc[4] += blo(v.z); acc[5] += bhi(v.z);
        acc[6] += blo(v.w); acc[7] += bhi(v.w);
    }
    uint4 q;
    q.x = pack2f(acc[0], acc[1]); q.y = pack2f(acc[2], acc[3]);
    q.z = pack2f(acc[4], acc[5]); q.w = pack2f(acc[6], acc[7]);
    *(uint4*)(D + (size_t)b * HID + lane * 8) = q;
}

// ---------------- GEMM 2 (hot): msg = relu([D | f_bonds] @ [W_h; W_i]) ----------------
// A (D region, kt<16) via global_load_lds with per-lane pre-swizzled source; double-buffered A+B.
// One barrier per glds K-step: __syncthreads' implicit vmcnt(0) drain waits exactly on step-kt loads
// (step kt+1 loads issued after the barrier stay in flight across compute).
__global__ __launch_bounds__(256, 4) void k_gemm_wh(
    const unsigned short* __restrict__ D, const float* __restrict__ fb,
    const unsigned short* __restrict__ WcatImg,
    unsigned short* __restrict__ msg_out)
{
    __shared__ unsigned short As[2][128][32];
    __shared__ unsigned short Bs[2][4096];
    const int orig = blockIdx.x;
    const int xcd = orig & 7, idx = orig >> 3;
    const int wg = (xcd < 4 ? xcd * 782 : 3128 + (xcd - 4) * 781) + idx;
    const int bm = wg >> 2, bn = wg & 3;
    const int row0 = bm * 128;

    const int tid = threadIdx.x, lane = tid & 63, wid = tid >> 6;
    const int wm = wid >> 1, wn = wid & 1;
    const int r0 = tid >> 2, c0 = tid & 3, r1 = 64 + r0;
    const int wsw = (c0 ^ ((r0 >> 1) & 3)) * 8;
    const int rsw = ((lane >> 4) ^ (((lane & 15) >> 1) & 3)) * 8;
    f32x4 acc[4][4] = {};

    // glds A sources (per-lane, swizzle folded into source column)
    const int arow1 = wid * 32 + (lane >> 2);
    const int arow2 = arow1 + 16;
    const int achk = lane & 3;
    const unsigned short* srcA1 = D + (size_t)min(row0 + arow1, B_N - 1) * HID + ((achk ^ ((arow1 >> 1) & 3)) << 3);
    const unsigned short* srcA2 = D + (size_t)min(row0 + arow2, B_N - 1) * HID + ((achk ^ ((arow2 >> 1) & 3)) << 3);
    const char* srcB = (const char*)WcatImg + (size_t)bn * 21 * 8192 + wid * 2048 + lane * 16;

    // fb region reg staging
    const int rg0 = min(row0 + r0, B_N - 1), rg1 = min(row0 + r1, B_N - 1);
    const float* pf0 = fb + (size_t)rg0 * BFD;
    const float* pf1 = fb + (size_t)rg1 * BFD;
    float v0[8], v1[8];

    // prologue: issue step-0 loads into buf0
    glds16(srcA1, &As[0][wid * 32][0]);
    glds16(srcA2, &As[0][wid * 32 + 16][0]);
    glds16(srcB, &Bs[0][wid * 1024]);
    glds16(srcB + 1024, &Bs[0][wid * 1024 + 512]);

    for (int kt = 0; kt < 21; ++kt) {
        const int cur = kt & 1, nxt = cur ^ 1;
        __syncthreads();   // step-kt loads landed (implicit vmcnt drain); prev compute done -> buf[nxt] free
        if (kt >= 16) {
            // A(kt) from regs (loaded during compute of kt-1)
            uint4 q;
            q.x = pack2f(v0[0], v0[1]); q.y = pack2f(v0[2], v0[3]); q.z = pack2f(v0[4], v0[5]); q.w = pack2f(v0[6], v0[7]);
            *(uint4*)&As[cur][r0][wsw] = q;
            q.x = pack2f(v1[0], v1[1]); q.y = pack2f(v1[2], v1[3]); q.z = pack2f(v1[4], v1[5]); q.w = pack2f(v1[6], v1[7]);
            *(uint4*)&As[cur][r1][wsw] = q;
            __syncthreads();   // fb A visible (lgkm drained); no glds issued yet this step
        }
        if (kt < 20) {
            if (kt + 1 < 16) {
                glds16(srcA1 + (kt + 1) * 32, &As[nxt][wid * 32][0]);
                glds16(srcA2 + (kt + 1) * 32, &As[nxt][wid * 32 + 16][0]);
            }
            glds16(srcB + (size_t)(kt + 1) * 8192, &Bs[nxt][wid * 1024]);
            glds16(srcB + (size_t)(kt + 1) * 8192 + 1024, &Bs[nxt][wid * 1024 + 512]);
        }
        if (kt >= 15 && kt < 20) {   // prefetch fb regs for step kt+1 (overlaps compute)
            int kb = (kt + 1) * 32 - HID + c0 * 8;
#pragma unroll
            for (int i = 0; i < 8; i++) { int kg = kb + i; v0[i] = (kg < BFD) ? pf0[kg] : 0.f; }
#pragma unroll
            for (int i = 0; i < 8; i++) { int kg = kb + i; v1[i] = (kg < BFD) ? pf1[kg] : 0.f; }
        }
        bf16x8 af[4], bfr[4];
#pragma unroll
        for (int m = 0; m < 4; m++) af[m] = *(const bf16x8*)&As[cur][wm * 64 + m * 16 + (lane & 15)][rsw];
#pragma unroll
        for (int n = 0; n < 4; n++) bfr[n] = *(const bf16x8*)&Bs[cur][(wn * 64 + n * 16 + (lane & 15)) * 32 + rsw];
#pragma unroll
        for (int m = 0; m < 4; m++)
#pragma unroll
            for (int n = 0; n < 4; n++)
                acc[m][n] = __builtin_amdgcn_mfma_f32_16x16x32_bf16(af[m], bfr[n], acc[m][n], 0, 0, 0);
    }

#pragma unroll
    for (int m = 0; m < 4; m++) {
        int rbase = row0 + wm * 64 + m * 16 + (lane >> 4) * 4;
#pragma unroll
        for (int n = 0; n < 4; n++) {
            int cg = bn * 128 + wn * 64 + n * 16 + (lane & 15);
#pragma unroll
            for (int r = 0; r < 4; r++) {
                int rg = rbase + r;
                if (rg < B_N) {
                    float v = acc[m][n][r];
                    msg_out[(size_t)rg * HID + cg] = f2b(v > 0.f ? v : 0.f);
                }
            }
        }
    }
}

// ---------------- GEMM 3: atom_hiddens = relu(concat(f_atoms, amsg) @ W_o + b_o) ----------------
// Same pipeline: kt 0..4 = fa f32 reg path (2-barrier), kt 5..20 = amsg via glds (1-barrier); B via glds all steps.
__global__ __launch_bounds__(256, 4) void k_gemm_wo(
    const float* __restrict__ fa, const unsigned short* __restrict__ amsg,
    const unsigned short* __restrict__ WoT, const float* __restrict__ bo,
    float* __restrict__ ah)
{
    __shared__ unsigned short As[2][128][32];
    __shared__ unsigned short Bs[2][128][32];
    const int orig = blockIdx.x;
    const int wg = (orig & 7) * 391 + (orig >> 3);   // nwg = 3128 = 8*391
    const int bm = wg >> 2, bn = wg & 3;
    const int row0 = bm * 128, col0 = bn * 128;

    const int tid = threadIdx.x, lane = tid & 63, wid = tid >> 6;
    const int wm = wid >> 1, wn = wid & 1;
    const int r0 = tid >> 2, c0 = tid & 3, r1 = 64 + r0;
    const int wsw = (c0 ^ ((r0 >> 1) & 3)) * 8;
    const int rsw = ((lane >> 4) ^ (((lane & 15) >> 1) & 3)) * 8;
    f32x4 acc[4][4] = {};

    // glds sources (per-lane, swizzled)
    const int grow1 = wid * 32 + (lane >> 2);
    const int grow2 = grow1 + 16;
    const int gchk = lane & 3;
    const int asw1 = (gchk ^ ((grow1 >> 1) & 3)) << 3;
    const int asw2 = (gchk ^ ((grow2 >> 1) & 3)) << 3;
    const unsigned short* srcA1 = amsg + (size_t)min(row0 + grow1, A_N - 1) * HID + asw1 - 160;
    const unsigned short* srcA2 = amsg + (size_t)min(row0 + grow2, A_N - 1) * HID + asw2 - 160;
    const unsigned short* srcB1 = WoT + (size_t)(col0 + grow1) * 672 + asw1;
    const unsigned short* srcB2 = WoT + (size_t)(col0 + grow2) * 672 + asw2;

    // fa region reg staging
    const int rg0 = min(row0 + r0, A_N - 1), rg1 = min(row0 + r1, A_N - 1);
    const float* pf0 = fa + (size_t)rg0 * AFD;
    const float* pf1 = fa + (size_t)rg1 * AFD;
    float v0[8], v1[8];

    // prologue: A(0) regs + B(0) glds
    {
        int kb = c0 * 8;
#pragma unroll
        for (int i = 0; i < 8; i++) { int kg = kb + i; v0[i] = (kg < AFD) ? pf0[kg] : 0.f; }
#pragma unroll
        for (int i = 0; i < 8; i++) { int kg = kb + i; v1[i] = (kg < AFD) ? pf1[kg] : 0.f; }
    }
    glds16(srcB1, &Bs[0][wid * 32][0]);
    glds16(srcB2, &Bs[0][wid * 32 + 16][0]);

    for (int kt = 0; kt < 21; ++kt) {
        const int cur = kt & 1, nxt = cur ^ 1;
        __syncthreads();   // step-kt glds landed; prev compute done
        if (kt < 5) {
            uint4 q;
            q.x = pack2f(v0[0], v0[1]); q.y = pack2f(v0[2], v0[3]); q.z = pack2f(v0[4], v0[5]); q.w = pack2f(v0[6], v0[7]);
            *(uint4*)&As[cur][r0][wsw] = q;
            q.x = pack2f(v1[0], v1[1]); q.y = pack2f(v1[2], v1[3]); q.z = pack2f(v1[4], v1[5]); q.w = pack2f(v1[6], v1[7]);
            *(uint4*)&As[cur][r1][wsw] = q;
            __syncthreads();
        }
        if (kt < 20) {
            if (kt + 1 >= 5) {
                glds16(srcA1 + (kt + 1) * 32, &As[nxt][wid * 32][0]);
                glds16(srcA2 + (kt + 1) * 32, &As[nxt][wid * 32 + 16][0]);
            }
            glds16(srcB1 + (kt + 1) * 32, &Bs[nxt][wid * 32][0]);
            glds16(srcB2 + (kt + 1) * 32, &Bs[nxt][wid * 32 + 16][0]);
        }
        if (kt < 4) {   // prefetch fa regs for step kt+1
            int kb = (kt + 1) * 32 + c0 * 8;
#pragma unroll
            for (int i = 0; i < 8; i++) { int kg = kb + i; v0[i] = (kg < AFD) ? pf0[kg] : 0.f; }
#pragma unroll
            for (int i = 0; i < 8; i++) { int kg = kb + i; v1[i] = (kg < AFD) ? pf1[kg] : 0.f; }
        }
        bf16x8 af[4], bfr[4];
#pragma unroll
        for (int m = 0; m < 4; m++) af[m] = *(const bf16x8*)&As[cur][wm * 64 + m * 16 + (lane & 15)][rsw];
#pragma unroll
        for (int n = 0; n < 4; n++) bfr[n] = *(const bf16x8*)&Bs[cur][wn * 64 + n * 16 + (lane & 15)][rsw];
#pragma unroll
        for (int m = 0; m < 4; m++)
#pragma unroll
            for (int n = 0; n < 4; n++)
                acc[m][n] = __builtin_amdgcn_mfma_f32_16x16x32_bf16(af[m], bfr[n], acc[m][n], 0, 0, 0);
    }

#pragma unroll
    for (int m = 0; m < 4; m++) {
        int rbase = row0 + wm * 64 + m * 16 + (lane >> 4) * 4;
#pragma unroll
        for (int n = 0; n < 4; n++) {
            int cg = col0 + wn * 64 + n * 16 + (lane & 15);
            float bias = bo[cg];
#pragma unroll
            for (int r = 0; r < 4; r++) {
                int rg = rbase + r;
                if (rg < A_N) {
                    float v = acc[m][n][r] + bias;
                    ah[(size_t)rg * HID + cg] = v > 0.f ? v : 0.f;
                }
            }
        }
    }
}

// ---------------- final gather-sum: amsg[a] = sum_k msg[a2b[a][k]] ----------------
__global__ __launch_bounds__(256) void k_gather(
    const unsigned short* __restrict__ msg, const int* __restrict__ a2b,
    unsigned short* __restrict__ amsg)
{
    int g = blockIdx.x * 4 + (threadIdx.x >> 6);
    if (g >= A_N) return;
    int lane = threadIdx.x & 63;
    const int* nb = a2b + (size_t)g * MAXNB;
    float acc[8] = {};
#pragma unroll
    for (int k = 0; k < MAXNB; k++) {
        uint4 v = *(const uint4*)(msg + (size_t)nb[k] * HID + lane * 8);
        acc[0] += blo(v.x); acc[1] += bhi(v.x);
        acc[2] += blo(v.y); acc[3] += bhi(v.y);
        acc[4] += blo(v.z); acc[5] += bhi(v.z);
        acc[6] += blo(v.w); acc[7] += bhi(v.w);
    }
    uint4 q;
    q.x = pack2f(acc[0], acc[1]); q.y = pack2f(acc[2], acc[3]);
    q.z = pack2f(acc[4], acc[5]); q.w = pack2f(acc[6], acc[7]);
    *(uint4*)(amsg + (size_t)g * HID + lane * 8) = q;
}

// ---------------- per-molecule mean (atom_to_mol is sorted) ----------------
__global__ __launch_bounds__(256) void k_segmean(
    const float* __restrict__ ah, const int* __restrict__ a2m, float* __restrict__ out)
{
    int mol = blockIdx.x, t = threadIdx.x;
    int lo, hi;
    { int l = 0, r = A_N; while (l < r) { int m = (l + r) >> 1; if (a2m[m] < mol) l = m + 1; else r = m; } lo = l; }
    { int l = lo, r = A_N; while (l < r) { int m = (l + r) >> 1; if (a2m[m] < mol + 1) l = m + 1; else r = m; } hi = l; }
    float s0 = 0.f, s1 = 0.f;
    for (int a = lo; a < hi; a++) {
        s0 += ah[(size_t)a * HID + t];
        s1 += ah[(size_t)a * HID + 256 + t];
    }
    int c = hi - lo;
    float inv = c > 0 ? 1.0f / (float)c : 0.f;
    out[(size_t)mol * HID + t] = s0 * inv;
    out[(size_t)mol * HID + 256 + t] = s1 * inv;
}

extern "C" void kernel_launch(void* const* d_in, const int* in_sizes, int n_in,
                              void* d_out, int out_size, void* d_ws, size_t ws_size,
                              hipStream_t stream)
{
    const float* f_atoms = (const float*)d_in[0];
    const float* f_bonds = (const float*)d_in[1];
    const float* W_i     = (const float*)d_in[2];
    const float* W_h     = (const float*)d_in[3];
    const float* W_o     = (const float*)d_in[4];
    const float* b_o     = (const float*)d_in[5];
    const int*   a2b     = (const int*)d_in[6];
    const int*   b2a     = (const int*)d_in[7];
    const int*   b2revb  = (const int*)d_in[8];
    const int*   a2m     = (const int*)d_in[9];

    const size_t OFF_MSG  = 0;              // bf16 [B,H] ; later f32 ah [A,H]
    const size_t OFF_D    = 204800000;      // bf16 [B,H] ; later bf16 amsg [A,H]
    const size_t OFF_WIT  = 409600000;      // 163,840
    const size_t OFF_WCAT = 409763840;      // 688,128 (pre-swizzled image)
    const size_t OFF_WOT  = 410451968;      // 688,128
    const size_t REQUIRED = 411140096;

    if (ws_size < REQUIRED) {
        float val = -(10000.0f + (float)(ws_size >> 20));
        k_diag<<<dim3((out_size + 255) / 256), dim3(256), 0, stream>>>((float*)d_out, out_size, val);
        return;
    }

    char* w = (char*)d_ws;
    unsigned short* msg   = (unsigned short*)(w + OFF_MSG);
    unsigned short* D     = (unsigned short*)(w + OFF_D);
    unsigned short* amsg  = (unsigned short*)(w + OFF_D);   // aliases D (dead after loop)
    unsigned short* WiT   = (unsigned short*)(w + OFF_WIT);
    unsigned short* Wcat  = (unsigned short*)(w + OFF_WCAT);
    unsigned short* WoT   = (unsigned short*)(w + OFF_WOT);
    float* ah             = (float*)(w + OFF_MSG);          // aliases msg (dead after gather)

    k_weights<<<dim3(512), dim3(256), 0, stream>>>(W_i, W_h, W_o, WiT, Wcat, WoT);
    k_gemm_wi<<<dim3(6252), dim3(256), 0, stream>>>(f_bonds, WiT, msg);
    for (int it = 0; it < 4; ++it) {
        k_delta<<<dim3(50000), dim3(256), 0, stream>>>(msg, a2b, b2a, b2revb, D);
        k_gemm_wh<<<dim3(6252), dim3(256), 0, stream>>>(D, f_bonds, Wcat, msg);
    }
    k_gather<<<dim3(25000), dim3(256), 0, stream>>>(msg, a2b, amsg);
    k_gemm_wo<<<dim3(3128), dim3(256), 0, stream>>>(f_atoms, amsg, WoT, b_o, ah);
    k_segmean<<<dim3(NMOL), dim3(256), 0, stream>>>(ah, a2m, (float*)d_out);
}